// Round 5
// baseline (738.728 us; speedup 1.0000x reference)
//
#include <hip/hip_runtime.h>

typedef unsigned short u16;
typedef __attribute__((ext_vector_type(4))) float f32x4;
typedef __attribute__((ext_vector_type(8))) short bf16x8;

constexpr int kB  = 4;
constexpr int kT  = 2048;
constexpr int kC  = 1024;
constexpr int kH  = 16;
constexpr int kFF = 4096;
constexpr int kM  = kB * kT;          // 8192 rows
constexpr int k3C = 3 * kC;           // 3072

__device__ __forceinline__ float b2f(u16 u) {
    union { unsigned int i; float f; } v;
    v.i = ((unsigned int)u) << 16;
    return v.f;
}
__device__ __forceinline__ u16 f2b(float f) {
    union { float f; unsigned int i; } v;
    v.f = f;
    unsigned int r = (v.i + 0x7FFFu + ((v.i >> 16) & 1u)) >> 16;
    return (u16)r;
}

// ---- f32 -> bf16 convert (x) -------------------------------------------------
__global__ void cvt_f32_bf16(const float* __restrict__ in, u16* __restrict__ out, int n4)
{
    const int i = blockIdx.x * 256 + threadIdx.x;
    if (i >= n4) return;
    float4 v = *(const float4*)(in + (size_t)i * 4);
    ushort4 o;
    o.x = f2b(v.x); o.y = f2b(v.y); o.z = f2b(v.z); o.w = f2b(v.w);
    *(ushort4*)(out + (size_t)i * 4) = o;
}

// ---- generic transpose+convert: in f32 [R][Cc] -> out bf16 [Cc][R] ----------
__global__ void transpose_cvt(const float* __restrict__ in, int R, int Cc,
                              u16* __restrict__ out)
{
    __shared__ float t[32][33];
    const int bx = blockIdx.x * 32;  // col base (Cc)
    const int by = blockIdx.y * 32;  // row base (R)
    const int lx = threadIdx.x, ly = threadIdx.y;  // (32, 8)
    #pragma unroll
    for (int i = 0; i < 32; i += 8)
        t[ly + i][lx] = in[(size_t)(by + ly + i) * Cc + bx + lx];
    __syncthreads();
    #pragma unroll
    for (int i = 0; i < 32; i += 8)
        out[(size_t)(bx + ly + i) * R + by + lx] = f2b(t[lx][ly + i]);
}

// ---- QKV weight repack: Wq/Wk/Wv [H,C,64] f32 -> Wqkv_t [3C][C] bf16 --------
__global__ void repack_qkv_t(const float* __restrict__ Wq, const float* __restrict__ Wk,
                             const float* __restrict__ Wv, u16* __restrict__ out)
{
    __shared__ float t[32][33];
    const int z = blockIdx.z;             // 48 = 3 * 16
    const int s = z >> 4, h = z & 15;
    const float* in = (s == 0 ? Wq : s == 1 ? Wk : Wv) + (size_t)h * (kC * 64);
    const int bx = blockIdx.x * 32;       // d base (0/32)
    const int by = blockIdx.y * 32;       // c base
    const int lx = threadIdx.x, ly = threadIdx.y;  // (32, 8)
    #pragma unroll
    for (int i = 0; i < 32; i += 8)
        t[ly + i][lx] = in[(size_t)(by + ly + i) * 64 + bx + lx];
    __syncthreads();
    const int orow = s * kC + h * 64 + bx;
    #pragma unroll
    for (int i = 0; i < 32; i += 8)
        out[(size_t)(orow + ly + i) * kC + by + lx] = f2b(t[lx][ly + i]);
}

// ---- bf16 MFMA GEMM: C[m,n] = A[M,K] @ Bt[N,K]^T (+bias)(relu)(+resid) ------
__global__ __launch_bounds__(256) void gemm_bt_mfma(
    const u16* __restrict__ A, int lda,
    const u16* __restrict__ Bt, int ldb,
    int K,
    const float* __restrict__ bias,
    const u16* __restrict__ resid,
    float* __restrict__ CoF,
    u16* __restrict__ CoB,
    int ldc, int do_relu)
{
    constexpr int BK = 64;
    __shared__ u16 As[128 * BK];
    __shared__ u16 Bs[128 * BK];
    const int tid  = threadIdx.x;
    const int wave = tid >> 6, lane = tid & 63;
    const int wm = (wave >> 1) * 64, wn = (wave & 1) * 64;
    const int m0 = blockIdx.y * 128, n0 = blockIdx.x * 128;

    const int srow = wave * 32;
    const int lrow = lane >> 3;
    const int scol = ((lane & 7) ^ lrow) * 8;

    const int fm   = lane & 15;
    const int fkq  = lane >> 4;

    f32x4 acc[4][4];
    #pragma unroll
    for (int i = 0; i < 4; ++i)
        #pragma unroll
        for (int j = 0; j < 4; ++j)
            acc[i][j] = (f32x4){0.f, 0.f, 0.f, 0.f};

    for (int k0 = 0; k0 < K; k0 += BK) {
        #pragma unroll
        for (int i = 0; i < 4; ++i) {
            const int r = srow + i * 8;
            const u16* ga = A  + (size_t)(m0 + r + lrow) * lda + k0 + scol;
            const u16* gb = Bt + (size_t)(n0 + r + lrow) * ldb + k0 + scol;
            __builtin_amdgcn_global_load_lds(
                (const __attribute__((address_space(1))) void*)ga,
                (__attribute__((address_space(3))) void*)&As[r * BK], 16, 0, 0);
            __builtin_amdgcn_global_load_lds(
                (const __attribute__((address_space(1))) void*)gb,
                (__attribute__((address_space(3))) void*)&Bs[r * BK], 16, 0, 0);
        }
        __syncthreads();
        #pragma unroll
        for (int ks = 0; ks < 2; ++ks) {
            bf16x8 a[4], b[4];
            #pragma unroll
            for (int i = 0; i < 4; ++i) {
                const int m = wm + i * 16 + fm;
                const int ck = ((ks * 4 + fkq) ^ (m & 7)) * 8;
                a[i] = *(const bf16x8*)&As[m * BK + ck];
            }
            #pragma unroll
            for (int j = 0; j < 4; ++j) {
                const int n = wn + j * 16 + fm;
                const int ck = ((ks * 4 + fkq) ^ (n & 7)) * 8;
                b[j] = *(const bf16x8*)&Bs[n * BK + ck];
            }
            #pragma unroll
            for (int i = 0; i < 4; ++i)
                #pragma unroll
                for (int j = 0; j < 4; ++j)
                    acc[i][j] = __builtin_amdgcn_mfma_f32_16x16x32_bf16(
                        a[i], b[j], acc[i][j], 0, 0, 0);
        }
        __syncthreads();
    }

    const int col = lane & 15;
    const int rb  = (lane >> 4) * 4;
    #pragma unroll
    for (int i = 0; i < 4; ++i) {
        #pragma unroll
        for (int j = 0; j < 4; ++j) {
            const int n = n0 + wn + j * 16 + col;
            #pragma unroll
            for (int r = 0; r < 4; ++r) {
                const int m = m0 + wm + i * 16 + rb + r;
                float v = acc[i][j][r];
                if (bias)    v += bias[n];
                if (do_relu) v = fmaxf(v, 0.f);
                if (resid)   v += b2f(resid[(size_t)m * ldc + n]);
                if (CoF) CoF[(size_t)m * ldc + n] = v;
                else     CoB[(size_t)m * ldc + n] = f2b(v);
            }
        }
    }
}

// ---- MFMA flash attention v2 ------------------------------------------------
// Block = 4 waves, Q-tile 128: wave w owns q rows [q0+32w, +32) as 2 fragments.
// K-tiles of 64. QK^T and PV via mfma_f32_16x16x32_bf16; P converts
// C/D->A layout through per-wave LDS. Swizzled LDS, conflict-free (<=2-way).
__global__ __launch_bounds__(256) void attn_mfma2(
    const u16* __restrict__ QKV, u16* __restrict__ Y)
{
    __shared__ __align__(16) u16 Kl[64 * 64];        // K-tile [s][d]   (8 KB)
    __shared__ __align__(16) u16 Vt[64 * 64];        // V-tile [d][s]   (8 KB)
    __shared__ __align__(16) u16 Pl[4 * 32 * 64];    // per-wave P [q][s] (16 KB)

    const int tid  = threadIdx.x;
    const int wave = tid >> 6, lane = tid & 63;
    const int ln   = lane & 15, quad = lane >> 4;
    const int qt = 15 - (int)blockIdx.x;             // heavy blocks first
    const int bh = blockIdx.y;
    const int b = bh >> 4, h = bh & 15;
    const int q0 = qt << 7;
    const int bT = b * kT;
    const int qgw = q0 + wave * 32;                  // wave's first q row
    const int wq_max = qgw + 31;
    const float scale = 0.03125f;                    // 1024^-0.5 (full embed dim)

    // Q fragments (A-operand): [qsub][ks]
    bf16x8 qa[2][2];
    #pragma unroll
    for (int qsub = 0; qsub < 2; ++qsub) {
        const size_t qb = ((size_t)bT + qgw + 16 * qsub + ln) * k3C + h * 64;
        qa[qsub][0] = *(const bf16x8*)(QKV + qb + quad * 8);
        qa[qsub][1] = *(const bf16x8*)(QKV + qb + 32 + quad * 8);
    }

    f32x4 acco[2][4];
    #pragma unroll
    for (int qsub = 0; qsub < 2; ++qsub)
        #pragma unroll
        for (int j = 0; j < 4; ++j) acco[qsub][j] = (f32x4){0.f, 0.f, 0.f, 0.f};
    float mrun[2][4], lrun[2][4];
    #pragma unroll
    for (int qsub = 0; qsub < 2; ++qsub)
        #pragma unroll
        for (int r = 0; r < 4; ++r) { mrun[qsub][r] = -1e30f; lrun[qsub][r] = 0.f; }

    u16* Pw = &Pl[wave * (32 * 64)];
    const int ntiles = (q0 >> 6) + 2;                // 2*qt + 2

    for (int t = 0; t < ntiles; ++t) {
        const int s0 = t << 6;
        // -- stage K [s][d] swizzled: 2 uint4 per thread --
        #pragma unroll
        for (int p = 0; p < 2; ++p) {
            const int id = tid + p * 256;
            const int s = id >> 3, c = id & 7;
            const u16* g = QKV + ((size_t)bT + s0 + s) * k3C + kC + h * 64 + c * 8;
            *(uint4*)&Kl[(s << 6) + (((c ^ (s & 7)) & 7) << 3)] = *(const uint4*)g;
        }
        // -- stage V transposed [d][s]: 2 uint4 loads, 8 ushort2 writes --
        {
            const int sp = tid >> 3, c = tid & 7;
            const int s = sp * 2;
            const u16* g = QKV + ((size_t)bT + s0 + s) * k3C + 2 * kC + h * 64 + c * 8;
            uint4 v0 = *(const uint4*)g;
            uint4 v1 = *(const uint4*)(g + k3C);
            u16 t0[8], t1[8];
            *(uint4*)t0 = v0; *(uint4*)t1 = v1;
            #pragma unroll
            for (int i = 0; i < 8; ++i) {
                const int d = c * 8 + i;
                const int chunk = ((s >> 3) ^ (d & 7) ^ ((d >> 3) & 7)) & 7;
                ushort2 pr; pr.x = t0[i]; pr.y = t1[i];
                *(ushort2*)&Vt[(d << 6) + (chunk << 3) + (s & 7)] = pr;
            }
        }
        __syncthreads();

        if (s0 <= wq_max) {  // wave has >=1 unmasked row in this K-tile
            // -- QK^T: 8 C/D tiles (2 qsub x 4 s-tiles) --
            f32x4 accs[2][4];
            #pragma unroll
            for (int qsub = 0; qsub < 2; ++qsub)
                #pragma unroll
                for (int j = 0; j < 4; ++j) accs[qsub][j] = (f32x4){0.f, 0.f, 0.f, 0.f};
            #pragma unroll
            for (int ks = 0; ks < 2; ++ks) {
                #pragma unroll
                for (int j = 0; j < 4; ++j) {
                    const int s = j * 16 + ln;
                    bf16x8 kb = *(const bf16x8*)&Kl[(s << 6) + ((((quad + 4 * ks) ^ (s & 7)) & 7) << 3)];
                    accs[0][j] = __builtin_amdgcn_mfma_f32_16x16x32_bf16(qa[0][ks], kb, accs[0][j], 0, 0, 0);
                    accs[1][j] = __builtin_amdgcn_mfma_f32_16x16x32_bf16(qa[1][ks], kb, accs[1][j], 0, 0, 0);
                }
            }
            // -- mask + scale --
            #pragma unroll
            for (int qsub = 0; qsub < 2; ++qsub) {
                #pragma unroll
                for (int j = 0; j < 4; ++j) {
                    const int sg = s0 + j * 16 + ln;
                    #pragma unroll
                    for (int r = 0; r < 4; ++r) {
                        const int qg = qgw + 16 * qsub + quad * 4 + r;
                        const float v = accs[qsub][j][r] * scale;
                        accs[qsub][j][r] = (sg <= qg) ? v : -1e30f;
                    }
                }
            }
            // -- online softmax: 8 independent q-row chains per lane --
            #pragma unroll
            for (int qsub = 0; qsub < 2; ++qsub) {
                #pragma unroll
                for (int r = 0; r < 4; ++r) {
                    float mx = fmaxf(fmaxf(accs[qsub][0][r], accs[qsub][1][r]),
                                     fmaxf(accs[qsub][2][r], accs[qsub][3][r]));
                    mx = fmaxf(mx, __shfl_xor(mx, 1));
                    mx = fmaxf(mx, __shfl_xor(mx, 2));
                    mx = fmaxf(mx, __shfl_xor(mx, 4));
                    mx = fmaxf(mx, __shfl_xor(mx, 8));
                    const float mn = fmaxf(mrun[qsub][r], mx);
                    const float al = __expf(mrun[qsub][r] - mn);
                    float ls = 0.f;
                    #pragma unroll
                    for (int j = 0; j < 4; ++j) {
                        const float p = __expf(accs[qsub][j][r] - mn);
                        accs[qsub][j][r] = p;
                        ls += p;
                    }
                    ls += __shfl_xor(ls, 1);
                    ls += __shfl_xor(ls, 2);
                    ls += __shfl_xor(ls, 4);
                    ls += __shfl_xor(ls, 8);
                    lrun[qsub][r] = lrun[qsub][r] * al + ls;
                    mrun[qsub][r] = mn;
                    #pragma unroll
                    for (int jd = 0; jd < 4; ++jd) acco[qsub][jd][r] *= al;
                }
            }
            // -- write P (C/D -> LDS [q][s], swizzled) --
            #pragma unroll
            for (int qsub = 0; qsub < 2; ++qsub) {
                #pragma unroll
                for (int j = 0; j < 4; ++j) {
                    const int s = j * 16 + ln;
                    #pragma unroll
                    for (int r = 0; r < 4; ++r) {
                        const int ql = 16 * qsub + quad * 4 + r;
                        Pw[(ql << 6) + ((((s >> 3) ^ (ql & 7)) & 7) << 3) + (s & 7)] =
                            f2b(accs[qsub][j][r]);
                    }
                }
            }
            // same-wave DS ordering: reads below wait on lgkmcnt for the writes
            bf16x8 pa[2][2];
            #pragma unroll
            for (int qsub = 0; qsub < 2; ++qsub) {
                const int ql = 16 * qsub + ln;
                #pragma unroll
                for (int ks = 0; ks < 2; ++ks)
                    pa[qsub][ks] = *(const bf16x8*)&Pw[(ql << 6) + ((((quad + 4 * ks) ^ (ql & 7)) & 7) << 3)];
            }
            // -- PV --
            #pragma unroll
            for (int jd = 0; jd < 4; ++jd) {
                const int d = jd * 16 + ln;
                #pragma unroll
                for (int ks = 0; ks < 2; ++ks) {
                    bf16x8 vb = *(const bf16x8*)&Vt[(d << 6) + ((((quad + 4 * ks) ^ (d & 7) ^ ((d >> 3) & 7)) & 7) << 3)];
                    acco[0][jd] = __builtin_amdgcn_mfma_f32_16x16x32_bf16(pa[0][ks], vb, acco[0][jd], 0, 0, 0);
                    acco[1][jd] = __builtin_amdgcn_mfma_f32_16x16x32_bf16(pa[1][ks], vb, acco[1][jd], 0, 0, 0);
                }
            }
        }
        __syncthreads();
    }

    // -- epilogue --
    #pragma unroll
    for (int qsub = 0; qsub < 2; ++qsub) {
        float inv[4];
        #pragma unroll
        for (int r = 0; r < 4; ++r) inv[r] = 1.f / lrun[qsub][r];
        #pragma unroll
        for (int jd = 0; jd < 4; ++jd) {
            const int col = h * 64 + jd * 16 + ln;
            #pragma unroll
            for (int r = 0; r < 4; ++r) {
                const int qg = qgw + 16 * qsub + quad * 4 + r;
                Y[((size_t)bT + qg) * kC + col] = f2b(acco[qsub][jd][r] * inv[r]);
            }
        }
    }
}

extern "C" void kernel_launch(void* const* d_in, const int* in_sizes, int n_in,
                              void* d_out, int out_size, void* d_ws, size_t ws_size,
                              hipStream_t stream) {
    const float* x     = (const float*)d_in[0];
    const float* Wq    = (const float*)d_in[1];
    const float* Wk    = (const float*)d_in[2];
    const float* Wv    = (const float*)d_in[3];
    const float* Wproj = (const float*)d_in[4];
    const float* bproj = (const float*)d_in[5];
    const float* W1    = (const float*)d_in[6];
    const float* b1    = (const float*)d_in[7];
    const float* W2    = (const float*)d_in[8];
    const float* b2    = (const float*)d_in[9];

    // Workspace (bf16 elements). QKV (live 2-3) aliases ffh (live 5-6).
    u16* ws      = (u16*)d_ws;
    u16* QKV     = ws;                                  // [8192,3072]
    u16* ffh     = ws;                                  // [8192,4096]
    u16* attn_y  = ws + (size_t)kM * kFF;               // [8192,1024]
    u16* xb      = attn_y  + (size_t)kM * kC;           // [8192,1024]
    u16* res1    = xb      + (size_t)kM * kC;           // [8192,1024]
    u16* Wqkv_t  = res1    + (size_t)kM * kC;           // [3072,1024]
    u16* Wproj_t = Wqkv_t  + (size_t)k3C * kC;          // [1024,1024]
    u16* W1t     = Wproj_t + (size_t)kC * kC;           // [4096,1024]
    u16* W2t     = W1t     + (size_t)kFF * kC;          // [1024,4096]
    float* out   = (float*)d_out;

    // 0. converts / repacks
    cvt_f32_bf16<<<(kM * kC / 4 + 255) / 256, 256, 0, stream>>>(x, xb, kM * kC / 4);
    repack_qkv_t<<<dim3(2, kC / 32, 48), dim3(32, 8), 0, stream>>>(Wq, Wk, Wv, Wqkv_t);
    transpose_cvt<<<dim3(kC / 32, kC / 32),  dim3(32, 8), 0, stream>>>(Wproj, kC, kC, Wproj_t);
    transpose_cvt<<<dim3(kFF / 32, kC / 32), dim3(32, 8), 0, stream>>>(W1, kC, kFF, W1t);
    transpose_cvt<<<dim3(kC / 32, kFF / 32), dim3(32, 8), 0, stream>>>(W2, kFF, kC, W2t);

    // 1. QKV = xb @ Wqkv_t^T
    gemm_bt_mfma<<<dim3(k3C / 128, kM / 128), 256, 0, stream>>>(
        xb, kC, Wqkv_t, kC, kC, nullptr, nullptr, nullptr, QKV, k3C, 0);
    // 2. attention -> attn_y bf16
    attn_mfma2<<<dim3(kT / 128, kB * kH), 256, 0, stream>>>(QKV, attn_y);
    // 3. res1 = attn_y @ Wproj + bproj + xb
    gemm_bt_mfma<<<dim3(kC / 128, kM / 128), 256, 0, stream>>>(
        attn_y, kC, Wproj_t, kC, kC, bproj, xb, nullptr, res1, kC, 0);
    // 4. ffh = relu(res1 @ W1 + b1)
    gemm_bt_mfma<<<dim3(kFF / 128, kM / 128), 256, 0, stream>>>(
        res1, kC, W1t, kC, kC, b1, nullptr, nullptr, ffh, kFF, 1);
    // 5. out = ffh @ W2 + b2 + res1 -> f32 (d_out)
    gemm_bt_mfma<<<dim3(kC / 128, kM / 128), 256, 0, stream>>>(
        ffh, kFF, W2t, kFF, kFF, b2, res1, out, nullptr, kC, 0);
}

// Round 6
// 609.759 us; speedup vs baseline: 1.2115x; 1.2115x over previous
//
#include <hip/hip_runtime.h>

typedef unsigned short u16;
typedef __attribute__((ext_vector_type(4))) float f32x4;
typedef __attribute__((ext_vector_type(8))) short bf16x8;

constexpr int kB  = 4;
constexpr int kT  = 2048;
constexpr int kC  = 1024;
constexpr int kH  = 16;
constexpr int kFF = 4096;
constexpr int kM  = kB * kT;          // 8192 rows
constexpr int k3C = 3 * kC;           // 3072

__device__ __forceinline__ float b2f(u16 u) {
    union { unsigned int i; float f; } v;
    v.i = ((unsigned int)u) << 16;
    return v.f;
}
__device__ __forceinline__ u16 f2b(float f) {
    union { float f; unsigned int i; } v;
    v.f = f;
    unsigned int r = (v.i + 0x7FFFu + ((v.i >> 16) & 1u)) >> 16;
    return (u16)r;
}

// lgkmcnt(0)-only barrier: LDS writes visible at the barrier, but outstanding
// global (vmcnt) prefetch loads stay in flight — enables cross-barrier pipelining.
__device__ __forceinline__ void lds_barrier() {
    __asm__ __volatile__("" ::: "memory");
    __builtin_amdgcn_s_waitcnt(0xC07F);   // vmcnt=63, expcnt=7, lgkmcnt=0
    __builtin_amdgcn_s_barrier();
    __asm__ __volatile__("" ::: "memory");
}

// ---- f32 -> bf16 convert (x) -------------------------------------------------
__global__ void cvt_f32_bf16(const float* __restrict__ in, u16* __restrict__ out, int n4)
{
    const int i = blockIdx.x * 256 + threadIdx.x;
    if (i >= n4) return;
    float4 v = *(const float4*)(in + (size_t)i * 4);
    ushort4 o;
    o.x = f2b(v.x); o.y = f2b(v.y); o.z = f2b(v.z); o.w = f2b(v.w);
    *(ushort4*)(out + (size_t)i * 4) = o;
}

// ---- generic transpose+convert: in f32 [R][Cc] -> out bf16 [Cc][R] ----------
__global__ void transpose_cvt(const float* __restrict__ in, int R, int Cc,
                              u16* __restrict__ out)
{
    __shared__ float t[32][33];
    const int bx = blockIdx.x * 32;  // col base (Cc)
    const int by = blockIdx.y * 32;  // row base (R)
    const int lx = threadIdx.x, ly = threadIdx.y;  // (32, 8)
    #pragma unroll
    for (int i = 0; i < 32; i += 8)
        t[ly + i][lx] = in[(size_t)(by + ly + i) * Cc + bx + lx];
    __syncthreads();
    #pragma unroll
    for (int i = 0; i < 32; i += 8)
        out[(size_t)(bx + ly + i) * R + by + lx] = f2b(t[lx][ly + i]);
}

// ---- QKV weight repack: Wq/Wk/Wv [H,C,64] f32 -> Wqkv_t [3C][C] bf16 --------
__global__ void repack_qkv_t(const float* __restrict__ Wq, const float* __restrict__ Wk,
                             const float* __restrict__ Wv, u16* __restrict__ out)
{
    __shared__ float t[32][33];
    const int z = blockIdx.z;             // 48 = 3 * 16
    const int s = z >> 4, h = z & 15;
    const float* in = (s == 0 ? Wq : s == 1 ? Wk : Wv) + (size_t)h * (kC * 64);
    const int bx = blockIdx.x * 32;       // d base (0/32)
    const int by = blockIdx.y * 32;       // c base
    const int lx = threadIdx.x, ly = threadIdx.y;  // (32, 8)
    #pragma unroll
    for (int i = 0; i < 32; i += 8)
        t[ly + i][lx] = in[(size_t)(by + ly + i) * 64 + bx + lx];
    __syncthreads();
    const int orow = s * kC + h * 64 + bx;
    #pragma unroll
    for (int i = 0; i < 32; i += 8)
        out[(size_t)(orow + ly + i) * kC + by + lx] = f2b(t[lx][ly + i]);
}

// ---- bf16 MFMA GEMM: C[m,n] = A[M,K] @ Bt[N,K]^T (+bias)(relu)(+resid) ------
__global__ __launch_bounds__(256) void gemm_bt_mfma(
    const u16* __restrict__ A, int lda,
    const u16* __restrict__ Bt, int ldb,
    int K,
    const float* __restrict__ bias,
    const u16* __restrict__ resid,
    float* __restrict__ CoF,
    u16* __restrict__ CoB,
    int ldc, int do_relu)
{
    constexpr int BK = 64;
    __shared__ u16 As[128 * BK];
    __shared__ u16 Bs[128 * BK];
    const int tid  = threadIdx.x;
    const int wave = tid >> 6, lane = tid & 63;
    const int wm = (wave >> 1) * 64, wn = (wave & 1) * 64;
    const int m0 = blockIdx.y * 128, n0 = blockIdx.x * 128;

    const int srow = wave * 32;
    const int lrow = lane >> 3;
    const int scol = ((lane & 7) ^ lrow) * 8;

    const int fm   = lane & 15;
    const int fkq  = lane >> 4;

    f32x4 acc[4][4];
    #pragma unroll
    for (int i = 0; i < 4; ++i)
        #pragma unroll
        for (int j = 0; j < 4; ++j)
            acc[i][j] = (f32x4){0.f, 0.f, 0.f, 0.f};

    for (int k0 = 0; k0 < K; k0 += BK) {
        #pragma unroll
        for (int i = 0; i < 4; ++i) {
            const int r = srow + i * 8;
            const u16* ga = A  + (size_t)(m0 + r + lrow) * lda + k0 + scol;
            const u16* gb = Bt + (size_t)(n0 + r + lrow) * ldb + k0 + scol;
            __builtin_amdgcn_global_load_lds(
                (const __attribute__((address_space(1))) void*)ga,
                (__attribute__((address_space(3))) void*)&As[r * BK], 16, 0, 0);
            __builtin_amdgcn_global_load_lds(
                (const __attribute__((address_space(1))) void*)gb,
                (__attribute__((address_space(3))) void*)&Bs[r * BK], 16, 0, 0);
        }
        __syncthreads();
        #pragma unroll
        for (int ks = 0; ks < 2; ++ks) {
            bf16x8 a[4], b[4];
            #pragma unroll
            for (int i = 0; i < 4; ++i) {
                const int m = wm + i * 16 + fm;
                const int ck = ((ks * 4 + fkq) ^ (m & 7)) * 8;
                a[i] = *(const bf16x8*)&As[m * BK + ck];
            }
            #pragma unroll
            for (int j = 0; j < 4; ++j) {
                const int n = wn + j * 16 + fm;
                const int ck = ((ks * 4 + fkq) ^ (n & 7)) * 8;
                b[j] = *(const bf16x8*)&Bs[n * BK + ck];
            }
            #pragma unroll
            for (int i = 0; i < 4; ++i)
                #pragma unroll
                for (int j = 0; j < 4; ++j)
                    acc[i][j] = __builtin_amdgcn_mfma_f32_16x16x32_bf16(
                        a[i], b[j], acc[i][j], 0, 0, 0);
        }
        __syncthreads();
    }

    const int col = lane & 15;
    const int rb  = (lane >> 4) * 4;
    #pragma unroll
    for (int i = 0; i < 4; ++i) {
        #pragma unroll
        for (int j = 0; j < 4; ++j) {
            const int n = n0 + wn + j * 16 + col;
            #pragma unroll
            for (int r = 0; r < 4; ++r) {
                const int m = m0 + wm + i * 16 + rb + r;
                float v = acc[i][j][r];
                if (bias)    v += bias[n];
                if (do_relu) v = fmaxf(v, 0.f);
                if (resid)   v += b2f(resid[(size_t)m * ldc + n]);
                if (CoF) CoF[(size_t)m * ldc + n] = v;
                else     CoB[(size_t)m * ldc + n] = f2b(v);
            }
        }
    }
}

// ---- MFMA flash attention v3 ------------------------------------------------
// Q-tile 128 (wave w: rows [q0+32w,+32) as 2 qsub), K-tiles 64.
// S^T = mfma(K,Q) so softmax axis = C/D rows -> 2-shuffle reductions, scalar
// alpha. O^T = mfma(V^T, P^T). Register double-buffered K/V staging with
// lgkm-only barrier (1/tile): global prefetch loads stay in flight across it.
__global__ __launch_bounds__(256) void attn_mfma3(
    const u16* __restrict__ QKV, u16* __restrict__ Y)
{
    __shared__ __align__(16) u16 Kl[2][64 * 64];     // 16 KB
    __shared__ __align__(16) u16 Vt[2][64 * 64];     // 16 KB (transposed [d][s])
    __shared__ __align__(16) u16 Pl[4][16 * 64];     // 8 KB per-wave P^T [q][s]

    const int tid  = threadIdx.x;
    const int wave = tid >> 6, lane = tid & 63;
    const int ln = lane & 15, quad = lane >> 4;
    const int idx = blockIdx.x;
    const int bh = idx & 63;                         // same bh -> same idx%8 (XCD)
    const int qt = 15 - (idx >> 6);                  // heavy q-tiles dispatch first
    const int b = bh >> 4, h = bh & 15;
    const int q0 = qt << 7;
    const int bT = b * kT;
    const int qgw = q0 + wave * 32;
    const float scale = 0.03125f;                    // 1024^-0.5 (full embed dim)

    const u16* kvbase = QKV + (size_t)bT * k3C + kC + h * 64;  // K base (V = +kC)

    // staging geometry
    const int sK = tid >> 3, cK = tid & 7;           // K rows sK, sK+32, chunk cK
    const int sV = (tid >> 3) * 2, cV = tid & 7;     // V rows sV, sV+1, chunk cV
    const int kwa0 = (sK << 6) + ((cK ^ (sK & 7)) << 3);
    const int kwa1 = kwa0 + (32 << 6);               // (sK+32)&7 == sK&7

    // Q fragments (B-operand of S^T): qa[qsub][ks]
    bf16x8 qa[2][2];
    #pragma unroll
    for (int qsub = 0; qsub < 2; ++qsub) {
        const size_t qb = ((size_t)bT + qgw + 16 * qsub + ln) * k3C + h * 64;
        qa[qsub][0] = *(const bf16x8*)(QKV + qb + quad * 8);
        qa[qsub][1] = *(const bf16x8*)(QKV + qb + 32 + quad * 8);
    }

    f32x4 acco[2][4];                                // O^T tiles: row d, col q=ln
    #pragma unroll
    for (int qsub = 0; qsub < 2; ++qsub)
        #pragma unroll
        for (int jd = 0; jd < 4; ++jd) acco[qsub][jd] = (f32x4){0.f, 0.f, 0.f, 0.f};
    float mrun[2] = {-1e30f, -1e30f}, lrun[2] = {0.f, 0.f};
    u16* Pw = Pl[wave];

    const int ntiles = 2 * qt + 2;                   // always even

    auto loadkv = [&](int s0p, uint4& k0, uint4& k1, uint4& v0, uint4& v1) {
        const u16* kg = kvbase + (size_t)(s0p + sK) * k3C + cK * 8;
        k0 = *(const uint4*)kg;
        k1 = *(const uint4*)(kg + (size_t)32 * k3C);
        const u16* vg = kvbase + kC + (size_t)(s0p + sV) * k3C + cV * 8;
        v0 = *(const uint4*)vg;
        v1 = *(const uint4*)(vg + k3C);
    };
    auto stage = [&](u16* Kb, u16* Vb, const uint4& k0, const uint4& k1,
                     const uint4& v0, const uint4& v1) {
        *(uint4*)&Kb[kwa0] = k0;
        *(uint4*)&Kb[kwa1] = k1;
        const u16* t0 = (const u16*)&v0;
        const u16* t1 = (const u16*)&v1;
        #pragma unroll
        for (int i = 0; i < 8; ++i) {
            const int d = cV * 8 + i;
            const int chunk = ((sV >> 3) ^ (d & 7) ^ ((d >> 3) & 7)) & 7;
            ushort2 pr; pr.x = t0[i]; pr.y = t1[i];
            *(ushort2*)&Vb[(d << 6) + (chunk << 3) + (sV & 7)] = pr;
        }
    };
    auto compute = [&](int t, const u16* Kb, const u16* Vb) {
        const int s0 = t << 6;
        if (s0 > qgw + 31) return;                   // wave fully masked this tile
        // S^T = K @ Q^T : rows s (quad*4+r within j-tile), cols q=ln
        f32x4 accs[2][4];
        #pragma unroll
        for (int qsub = 0; qsub < 2; ++qsub)
            #pragma unroll
            for (int j = 0; j < 4; ++j) accs[qsub][j] = (f32x4){0.f, 0.f, 0.f, 0.f};
        #pragma unroll
        for (int ks = 0; ks < 2; ++ks) {
            #pragma unroll
            for (int j = 0; j < 4; ++j) {
                const int s = j * 16 + ln;
                bf16x8 kb = *(const bf16x8*)&Kb[(s << 6) + ((((quad + 4 * ks) ^ (s & 7)) & 7) << 3)];
                accs[0][j] = __builtin_amdgcn_mfma_f32_16x16x32_bf16(kb, qa[0][ks], accs[0][j], 0, 0, 0);
                accs[1][j] = __builtin_amdgcn_mfma_f32_16x16x32_bf16(kb, qa[1][ks], accs[1][j], 0, 0, 0);
            }
        }
        // V^T A-frags (shared across qsub)
        bf16x8 vfr[4][2];
        #pragma unroll
        for (int jd = 0; jd < 4; ++jd) {
            const int d = jd * 16 + ln;
            #pragma unroll
            for (int ks = 0; ks < 2; ++ks)
                vfr[jd][ks] = *(const bf16x8*)&Vb[(d << 6) + ((((quad + 4 * ks) ^ (d & 7) ^ ((d >> 3) & 7)) & 7) << 3)];
        }
        #pragma unroll
        for (int qsub = 0; qsub < 2; ++qsub) {
            const int qg = qgw + 16 * qsub + ln;     // this lane's q column
            float part = -1e30f;
            #pragma unroll
            for (int j = 0; j < 4; ++j) {
                #pragma unroll
                for (int r = 0; r < 4; ++r) {
                    const int sg = s0 + j * 16 + quad * 4 + r;
                    float v = accs[qsub][j][r] * scale;
                    v = (sg <= qg) ? v : -1e30f;
                    accs[qsub][j][r] = v;
                    part = fmaxf(part, v);
                }
            }
            float mx = fmaxf(part, __shfl_xor(part, 16));
            mx = fmaxf(mx, __shfl_xor(mx, 32));
            const float mn = fmaxf(mrun[qsub], mx);
            const float al = __expf(mrun[qsub] - mn);
            mrun[qsub] = mn;
            float ls = 0.f;
            #pragma unroll
            for (int j = 0; j < 4; ++j)
                #pragma unroll
                for (int r = 0; r < 4; ++r) {
                    const float p = __expf(accs[qsub][j][r] - mn);
                    accs[qsub][j][r] = p;
                    ls += p;
                }
            ls += __shfl_xor(ls, 16);
            ls += __shfl_xor(ls, 32);
            lrun[qsub] = lrun[qsub] * al + ls;
            #pragma unroll
            for (int jd = 0; jd < 4; ++jd)
                #pragma unroll
                for (int r = 0; r < 4; ++r)
                    acco[qsub][jd][r] *= al;
            // P^T -> per-wave LDS [q=ln][s], chunk-8 swizzle; b64 writes
            #pragma unroll
            for (int j = 0; j < 4; ++j) {
                ushort4 pk;
                pk.x = f2b(accs[qsub][j][0]); pk.y = f2b(accs[qsub][j][1]);
                pk.z = f2b(accs[qsub][j][2]); pk.w = f2b(accs[qsub][j][3]);
                const int chunk = ((2 * j + (quad >> 1)) ^ (ln & 7)) & 7;
                *(ushort4*)&Pw[(ln << 6) + (chunk << 3) + ((quad & 1) << 2)] = pk;
            }
            // B-frag reads (same-wave DS ops are in-order) + PV
            #pragma unroll
            for (int ks = 0; ks < 2; ++ks) {
                bf16x8 pb = *(const bf16x8*)&Pw[(ln << 6) + ((((4 * ks + quad) ^ (ln & 7)) & 7) << 3)];
                #pragma unroll
                for (int jd = 0; jd < 4; ++jd)
                    acco[qsub][jd] = __builtin_amdgcn_mfma_f32_16x16x32_bf16(
                        vfr[jd][ks], pb, acco[qsub][jd], 0, 0, 0);
            }
        }
    };

    uint4 ka0, ka1, va0, va1, kb0, kb1, vb0, vb1;
    loadkv(0, ka0, ka1, va0, va1);
    for (int t = 0; t < ntiles; t += 2) {
        stage(Kl[0], Vt[0], ka0, ka1, va0, va1);
        loadkv((t + 1) << 6, kb0, kb1, vb0, vb1);    // t+1 < ntiles (ntiles even)
        lds_barrier();
        compute(t, Kl[0], Vt[0]);
        stage(Kl[1], Vt[1], kb0, kb1, vb0, vb1);
        loadkv(((t + 2) < ntiles ? (t + 2) : 0) << 6, ka0, ka1, va0, va1);
        lds_barrier();
        compute(t + 1, Kl[1], Vt[1]);
    }

    // epilogue: O^T row d = jd*16 + quad*4 + r, col q = ln; contiguous d x4 store
    #pragma unroll
    for (int qsub = 0; qsub < 2; ++qsub) {
        const float inv = 1.f / lrun[qsub];
        const size_t yrow = ((size_t)bT + qgw + 16 * qsub + ln) * kC + h * 64;
        #pragma unroll
        for (int jd = 0; jd < 4; ++jd) {
            ushort4 ov;
            ov.x = f2b(acco[qsub][jd][0] * inv);
            ov.y = f2b(acco[qsub][jd][1] * inv);
            ov.z = f2b(acco[qsub][jd][2] * inv);
            ov.w = f2b(acco[qsub][jd][3] * inv);
            *(ushort4*)(Y + yrow + jd * 16 + quad * 4) = ov;
        }
    }
}

extern "C" void kernel_launch(void* const* d_in, const int* in_sizes, int n_in,
                              void* d_out, int out_size, void* d_ws, size_t ws_size,
                              hipStream_t stream) {
    const float* x     = (const float*)d_in[0];
    const float* Wq    = (const float*)d_in[1];
    const float* Wk    = (const float*)d_in[2];
    const float* Wv    = (const float*)d_in[3];
    const float* Wproj = (const float*)d_in[4];
    const float* bproj = (const float*)d_in[5];
    const float* W1    = (const float*)d_in[6];
    const float* b1    = (const float*)d_in[7];
    const float* W2    = (const float*)d_in[8];
    const float* b2    = (const float*)d_in[9];

    // Workspace (bf16 elements). QKV (live 2-3) aliases ffh (live 5-6).
    u16* ws      = (u16*)d_ws;
    u16* QKV     = ws;                                  // [8192,3072]
    u16* ffh     = ws;                                  // [8192,4096]
    u16* attn_y  = ws + (size_t)kM * kFF;               // [8192,1024]
    u16* xb      = attn_y  + (size_t)kM * kC;           // [8192,1024]
    u16* res1    = xb      + (size_t)kM * kC;           // [8192,1024]
    u16* Wqkv_t  = res1    + (size_t)kM * kC;           // [3072,1024]
    u16* Wproj_t = Wqkv_t  + (size_t)k3C * kC;          // [1024,1024]
    u16* W1t     = Wproj_t + (size_t)kC * kC;           // [4096,1024]
    u16* W2t     = W1t     + (size_t)kFF * kC;          // [1024,4096]
    float* out   = (float*)d_out;

    // 0. converts / repacks
    cvt_f32_bf16<<<(kM * kC / 4 + 255) / 256, 256, 0, stream>>>(x, xb, kM * kC / 4);
    repack_qkv_t<<<dim3(2, kC / 32, 48), dim3(32, 8), 0, stream>>>(Wq, Wk, Wv, Wqkv_t);
    transpose_cvt<<<dim3(kC / 32, kC / 32),  dim3(32, 8), 0, stream>>>(Wproj, kC, kC, Wproj_t);
    transpose_cvt<<<dim3(kFF / 32, kC / 32), dim3(32, 8), 0, stream>>>(W1, kC, kFF, W1t);
    transpose_cvt<<<dim3(kC / 32, kFF / 32), dim3(32, 8), 0, stream>>>(W2, kFF, kC, W2t);

    // 1. QKV = xb @ Wqkv_t^T
    gemm_bt_mfma<<<dim3(k3C / 128, kM / 128), 256, 0, stream>>>(
        xb, kC, Wqkv_t, kC, kC, nullptr, nullptr, nullptr, QKV, k3C, 0);
    // 2. attention -> attn_y bf16
    attn_mfma3<<<dim3(1024), 256, 0, stream>>>(QKV, attn_y);
    // 3. res1 = attn_y @ Wproj + bproj + xb
    gemm_bt_mfma<<<dim3(kC / 128, kM / 128), 256, 0, stream>>>(
        attn_y, kC, Wproj_t, kC, kC, bproj, xb, nullptr, res1, kC, 0);
    // 4. ffh = relu(res1 @ W1 + b1)
    gemm_bt_mfma<<<dim3(kFF / 128, kM / 128), 256, 0, stream>>>(
        res1, kC, W1t, kC, kC, b1, nullptr, nullptr, ffh, kFF, 1);
    // 5. out = ffh @ W2 + b2 + res1 -> f32 (d_out)
    gemm_bt_mfma<<<dim3(kC / 128, kM / 128), 256, 0, stream>>>(
        ffh, kFF, W2t, kFF, kFF, b2, res1, out, nullptr, kC, 0);
}